// Round 10
// baseline (219.467 us; speedup 1.0000x reference)
//
#include <hip/hip_runtime.h>

typedef float f32x4 __attribute__((ext_vector_type(4)));

#define EPSV 1e-5f

__device__ __forceinline__ float sigmoidf_(float z) {
    return 1.0f / (1.0f + __expf(-z));
}

// ---------------------------------------------------------------------------
// ONE dispatch, 512-thread blocks, two interleaved families:
//   bid % 5 == 0 -> x1 family (block id bid/5): one (b,g) group per block.
//       Phase 1: stream the 6272-f4 x1 slab (12-13 f4/thread), accumulate
//                sum/sumsq (values discarded - no staging fiction).
//       Reduce:  wave shfl + 8-slot LDS, finalize per-channel affine (A,B).
//       Phase 2: explicit re-read (L2/L3-hot), gate, nt-store.
//   else         -> x0 family: wave-per-channel, barrier-free: load 196 f4,
//                shfl-reduce mean, sigmoid gate, nt-store.
// Interleave puts ~4 streaming x0 blocks next to each x1 block on a CU, so
// x1's barrier/reduce stalls overlap with x0's pure streaming.
// ---------------------------------------------------------------------------
__global__ __launch_bounds__(512, 8) void fused_sgate_mix(
    const f32x4* __restrict__ x4,
    const float* __restrict__ cweight,
    const float* __restrict__ cbias,
    const float* __restrict__ sweight,
    const float* __restrict__ sbias,
    f32x4* __restrict__ out4)
{
    const int bid = (int)blockIdx.x;
    const int tid = threadIdx.x;

    if (bid % 5 == 0) {
        // ================= x1 family =================
        const int bg = bid / 5;
        const int b  = bg >> 3, g = bg & 7;
        const f32x4* __restrict__ xs = x4 + (size_t)bg * 12544 + 6272;

        // Phase 1: streaming sum/sumsq (12 f4/thread + 128 extras)
        float s = 0.f, ss = 0.f;
#pragma unroll
        for (int k = 0; k < 12; ++k) {
            f32x4 v = xs[tid + 512 * k];
            s  += (v.x + v.y) + (v.z + v.w);
            ss += (v.x * v.x + v.y * v.y) + (v.z * v.z + v.w * v.w);
        }
        const bool x1e = (tid < 128);
        if (x1e) {
            f32x4 v = xs[6144 + tid];
            s  += (v.x + v.y) + (v.z + v.w);
            ss += (v.x * v.x + v.y * v.y) + (v.z * v.z + v.w * v.w);
        }

#pragma unroll
        for (int m = 32; m >= 1; m >>= 1) {
            s  += __shfl_xor(s,  m, 64);
            ss += __shfl_xor(ss, m, 64);
        }

        __shared__ float lds_s[8], lds_ss[8];
        __shared__ float ldsA[32], ldsB[32];
        if ((tid & 63) == 0) { lds_s[tid >> 6] = s; lds_ss[tid >> 6] = ss; }
        __syncthreads();

        if (tid < 32) {
            float S = 0.f, SS = 0.f;
#pragma unroll
            for (int i = 0; i < 8; ++i) { S += lds_s[i]; SS += lds_ss[i]; }
            constexpr float inv_n = 1.0f / (32.0f * 784.0f);
            const float mu   = S * inv_n;
            const float var  = SS * inv_n - mu * mu;
            const float rstd = rsqrtf(fmaxf(var, 0.f) + EPSV);
            const float A    = sweight[tid] * rstd;
            ldsA[tid] = A;
            ldsB[tid] = sbias[tid] - A * mu;
        }
        __syncthreads();

        // Phase 2: explicit L2-hot re-read, gate, nt-store
        f32x4* __restrict__ ob = out4 + (size_t)b * 100352;
#pragma unroll
        for (int k = 0; k < 12; ++k) {
            const int idx = tid + 512 * k;
            const int c1  = idx / 196;
            const int p   = idx - c1 * 196;
            const float A = ldsA[c1], Bq = ldsB[c1];
            f32x4 t = xs[idx], r;
            r.x = t.x * sigmoidf_(A * t.x + Bq);
            r.y = t.y * sigmoidf_(A * t.y + Bq);
            r.z = t.z * sigmoidf_(A * t.z + Bq);
            r.w = t.w * sigmoidf_(A * t.w + Bq);
            const int c  = g * 64 + 32 + c1;
            const int cp = (c < 256) ? (2 * c) : (2 * (c - 256) + 1);
            __builtin_nontemporal_store(r, ob + (size_t)cp * 196 + p);
        }
        if (x1e) {
            const int idx = 6144 + tid;
            const int c1  = idx / 196;
            const int p   = idx - c1 * 196;
            const float A = ldsA[c1], Bq = ldsB[c1];
            f32x4 t = xs[idx], r;
            r.x = t.x * sigmoidf_(A * t.x + Bq);
            r.y = t.y * sigmoidf_(A * t.y + Bq);
            r.z = t.z * sigmoidf_(A * t.z + Bq);
            r.w = t.w * sigmoidf_(A * t.w + Bq);
            const int c  = g * 64 + 32 + c1;
            const int cp = (c < 256) ? (2 * c) : (2 * (c - 256) + 1);
            __builtin_nontemporal_store(r, ob + (size_t)cp * 196 + p);
        }
    } else {
        // ================= x0 family: wave-per-channel, barrier-free =======
        const int x0id = bid - bid / 5 - 1;            // 0 .. nX0-1
        const int chw  = x0id * 8 + (tid >> 6);        // global x0 channel
        const int ln   = tid & 63;
        const int bg   = chw >> 5;                     // 32 x0-channels/group
        const int cc   = chw & 31;

        const f32x4* __restrict__ xch = x4 + (size_t)bg * 12544 + cc * 196;
        f32x4 v0 = xch[ln];
        f32x4 v1 = xch[64 + ln];
        f32x4 v2 = xch[128 + ln];
        const bool extra = (ln < 4);
        f32x4 v3 = {0.f, 0.f, 0.f, 0.f};
        if (extra) v3 = xch[192 + ln];

        float s = (v0.x + v0.y) + (v0.z + v0.w)
                + (v1.x + v1.y) + (v1.z + v1.w)
                + (v2.x + v2.y) + (v2.z + v2.w)
                + (v3.x + v3.y) + (v3.z + v3.w);
#pragma unroll
        for (int m = 32; m >= 1; m >>= 1) s += __shfl_xor(s, m, 64);

        const float a0 = sigmoidf_(cweight[cc] * (s * (1.0f / 784.0f)) + cbias[cc]);

        const int b = bg >> 3, g = bg & 7;
        const int c  = g * 64 + cc;
        const int cp = (c < 256) ? (2 * c) : (2 * (c - 256) + 1);
        f32x4* __restrict__ och = out4 + (size_t)b * 100352 + (size_t)cp * 196;

        __builtin_nontemporal_store(v0 * a0, &och[ln]);
        __builtin_nontemporal_store(v1 * a0, &och[64 + ln]);
        __builtin_nontemporal_store(v2 * a0, &och[128 + ln]);
        if (extra) __builtin_nontemporal_store(v3 * a0, &och[192 + ln]);
    }
}

extern "C" void kernel_launch(void* const* d_in, const int* in_sizes, int n_in,
                              void* d_out, int out_size, void* d_ws, size_t ws_size,
                              hipStream_t stream) {
    const float* x  = (const float*)d_in[0];
    const float* cw = (const float*)d_in[1];
    const float* cb = (const float*)d_in[2];
    const float* sw = (const float*)d_in[3];
    const float* sb = (const float*)d_in[4];
    float* out = (float*)d_out;

    const int B   = in_sizes[0] / (512 * 784);
    const int nX1 = B * 8;     // one x1 block per (b,g) group
    const int nX0 = B * 32;    // B*8*32 channels / 8 waves per block
    // nX0 == 4*nX1, so grid = 5*nX1 with pattern [x1, x0, x0, x0, x0]

    fused_sgate_mix<<<nX1 + nX0, 512, 0, stream>>>(
        (const f32x4*)x, cw, cb, sw, sb, (f32x4*)out);
}

// Round 11
// 191.652 us; speedup vs baseline: 1.1451x; 1.1451x over previous
//
#include <hip/hip_runtime.h>

typedef float f32x4 __attribute__((ext_vector_type(4)));

#define EPSV 1e-5f

__device__ __forceinline__ float sigmoidf_(float z) {
    return 1.0f / (1.0f + __expf(-z));
}

// ---------------------------------------------------------------------------
// ONE dispatch, 1024-thread blocks, families batched (x1 first, then x0).
//
// x1 family (blocks [0,nX1)): one (b,g) group per block. The 6272-float4 x1
// slab is staged ON-CHIP: 4096 f4 in 64 KB LDS + 2176 f4 in registers
// (2 f4/thread + 128 extras). Phase 1 accumulates sum/sumsq while staging;
// after the stats barrier, phase 2 gates from LDS/regs and stores. No global
// re-read — HBM traffic is structurally 1 read + 1 write.
// 64 KB LDS + 16 waves -> exactly 2 blocks/CU = full 32-wave occupancy.
//
// x0 family (blocks [nX1,...)): wave-per-channel, barrier-free (R8-proven).
//
// All stores are NORMAL (nt dropped) - isolating the store-path variable.
// ---------------------------------------------------------------------------
__global__ __launch_bounds__(1024, 8) void fused_sgate_lds(
    const f32x4* __restrict__ x4,
    const float* __restrict__ cweight,
    const float* __restrict__ cbias,
    const float* __restrict__ sweight,
    const float* __restrict__ sbias,
    f32x4* __restrict__ out4,
    int nX1)
{
    const int tid = threadIdx.x;

    if ((int)blockIdx.x < nX1) {
        // ================= x1 family =================
        const int bg = blockIdx.x;
        const int b  = bg >> 3, g = bg & 7;
        const f32x4* __restrict__ xs = x4 + (size_t)bg * 12544 + 6272;

        __shared__ f32x4 slab[4096];              // 64 KB
        __shared__ float lds_s[16], lds_ss[16];
        __shared__ float ldsA[32], ldsB[32];

        // ---- phase 1: load + stage + accumulate ----
        f32x4 t0 = xs[tid];
        f32x4 t1 = xs[1024 + tid];
        f32x4 t2 = xs[2048 + tid];
        f32x4 t3 = xs[3072 + tid];
        f32x4 w0 = xs[4096 + tid];
        f32x4 w1 = xs[5120 + tid];
        const bool x1e = (tid < 128);
        f32x4 we = {0.f, 0.f, 0.f, 0.f};
        if (x1e) we = xs[6144 + tid];

        slab[tid]        = t0;
        slab[1024 + tid] = t1;
        slab[2048 + tid] = t2;
        slab[3072 + tid] = t3;

        float s, ss;
        {
            f32x4 a = t0 + t1, c = t2 + t3, d = w0 + w1;
            f32x4 q = t0 * t0 + t1 * t1 + t2 * t2 + t3 * t3
                    + w0 * w0 + w1 * w1 + we * we;
            f32x4 sv = a + c + d + we;
            s  = (sv.x + sv.y) + (sv.z + sv.w);
            ss = (q.x + q.y) + (q.z + q.w);
        }

#pragma unroll
        for (int m = 32; m >= 1; m >>= 1) {
            s  += __shfl_xor(s,  m, 64);
            ss += __shfl_xor(ss, m, 64);
        }
        if ((tid & 63) == 0) { lds_s[tid >> 6] = s; lds_ss[tid >> 6] = ss; }
        __syncthreads();

        if (tid < 32) {
            float S = 0.f, SS = 0.f;
#pragma unroll
            for (int i = 0; i < 16; ++i) { S += lds_s[i]; SS += lds_ss[i]; }
            constexpr float inv_n = 1.0f / (32.0f * 784.0f);
            const float mu   = S * inv_n;
            const float var  = SS * inv_n - mu * mu;
            const float rstd = rsqrtf(fmaxf(var, 0.f) + EPSV);
            const float A    = sweight[tid] * rstd;
            ldsA[tid] = A;
            ldsB[tid] = sbias[tid] - A * mu;
        }
        __syncthreads();

        // pin the register-staged tail across the barrier
        asm volatile("" : "+v"(w0.x), "+v"(w0.y), "+v"(w0.z), "+v"(w0.w),
                          "+v"(w1.x), "+v"(w1.y), "+v"(w1.z), "+v"(w1.w));

        // ---- phase 2: gate from LDS/regs, store ----
        f32x4* __restrict__ ob = out4 + (size_t)b * 100352;
#pragma unroll
        for (int k = 0; k < 4; ++k) {
            const int idx = tid + 1024 * k;
            const int c1  = idx / 196;
            const int p   = idx - c1 * 196;
            const float A = ldsA[c1], Bq = ldsB[c1];
            f32x4 v = slab[idx], r;
            r.x = v.x * sigmoidf_(A * v.x + Bq);
            r.y = v.y * sigmoidf_(A * v.y + Bq);
            r.z = v.z * sigmoidf_(A * v.z + Bq);
            r.w = v.w * sigmoidf_(A * v.w + Bq);
            const int c  = g * 64 + 32 + c1;
            const int cp = (c < 256) ? (2 * c) : (2 * (c - 256) + 1);
            ob[(size_t)cp * 196 + p] = r;
        }
        {   // idx = 4096 + tid (from w0)
            const int idx = 4096 + tid;
            const int c1  = idx / 196;
            const int p   = idx - c1 * 196;
            const float A = ldsA[c1], Bq = ldsB[c1];
            f32x4 r;
            r.x = w0.x * sigmoidf_(A * w0.x + Bq);
            r.y = w0.y * sigmoidf_(A * w0.y + Bq);
            r.z = w0.z * sigmoidf_(A * w0.z + Bq);
            r.w = w0.w * sigmoidf_(A * w0.w + Bq);
            const int c  = g * 64 + 32 + c1;
            const int cp = (c < 256) ? (2 * c) : (2 * (c - 256) + 1);
            ob[(size_t)cp * 196 + p] = r;
        }
        {   // idx = 5120 + tid (from w1)
            const int idx = 5120 + tid;
            const int c1  = idx / 196;
            const int p   = idx - c1 * 196;
            const float A = ldsA[c1], Bq = ldsB[c1];
            f32x4 r;
            r.x = w1.x * sigmoidf_(A * w1.x + Bq);
            r.y = w1.y * sigmoidf_(A * w1.y + Bq);
            r.z = w1.z * sigmoidf_(A * w1.z + Bq);
            r.w = w1.w * sigmoidf_(A * w1.w + Bq);
            const int c  = g * 64 + 32 + c1;
            const int cp = (c < 256) ? (2 * c) : (2 * (c - 256) + 1);
            ob[(size_t)cp * 196 + p] = r;
        }
        if (x1e) {  // idx = 6144 + tid (from we)
            const int idx = 6144 + tid;
            const int c1  = idx / 196;
            const int p   = idx - c1 * 196;
            const float A = ldsA[c1], Bq = ldsB[c1];
            f32x4 r;
            r.x = we.x * sigmoidf_(A * we.x + Bq);
            r.y = we.y * sigmoidf_(A * we.y + Bq);
            r.z = we.z * sigmoidf_(A * we.z + Bq);
            r.w = we.w * sigmoidf_(A * we.w + Bq);
            const int c  = g * 64 + 32 + c1;
            const int cp = (c < 256) ? (2 * c) : (2 * (c - 256) + 1);
            ob[(size_t)cp * 196 + p] = r;
        }
    } else {
        // ================= x0 family: wave-per-channel, barrier-free =======
        const int chw = ((int)blockIdx.x - nX1) * 16 + (tid >> 6);
        const int ln  = tid & 63;
        const int bg  = chw >> 5;          // 32 x0-channels per group
        const int cc  = chw & 31;

        const f32x4* __restrict__ xch = x4 + (size_t)bg * 12544 + cc * 196;
        f32x4 v0 = xch[ln];
        f32x4 v1 = xch[64 + ln];
        f32x4 v2 = xch[128 + ln];
        const bool extra = (ln < 4);
        f32x4 v3 = {0.f, 0.f, 0.f, 0.f};
        if (extra) v3 = xch[192 + ln];

        float s = (v0.x + v0.y) + (v0.z + v0.w)
                + (v1.x + v1.y) + (v1.z + v1.w)
                + (v2.x + v2.y) + (v2.z + v2.w)
                + (v3.x + v3.y) + (v3.z + v3.w);
#pragma unroll
        for (int m = 32; m >= 1; m >>= 1) s += __shfl_xor(s, m, 64);

        const float a0 = sigmoidf_(cweight[cc] * (s * (1.0f / 784.0f)) + cbias[cc]);

        const int b = bg >> 3, g = bg & 7;
        const int c  = g * 64 + cc;
        const int cp = (c < 256) ? (2 * c) : (2 * (c - 256) + 1);
        f32x4* __restrict__ och = out4 + (size_t)b * 100352 + (size_t)cp * 196;

        och[ln]       = v0 * a0;
        och[64 + ln]  = v1 * a0;
        och[128 + ln] = v2 * a0;
        if (extra) och[192 + ln] = v3 * a0;
    }
}

extern "C" void kernel_launch(void* const* d_in, const int* in_sizes, int n_in,
                              void* d_out, int out_size, void* d_ws, size_t ws_size,
                              hipStream_t stream) {
    const float* x  = (const float*)d_in[0];
    const float* cw = (const float*)d_in[1];
    const float* cb = (const float*)d_in[2];
    const float* sw = (const float*)d_in[3];
    const float* sb = (const float*)d_in[4];
    float* out = (float*)d_out;

    const int B   = in_sizes[0] / (512 * 784);
    const int nX1 = B * 8;                 // one block per (b,g) group
    const int nX0 = B * 16;                // B*8*32 channel-waves / 16 per block

    fused_sgate_lds<<<nX1 + nX0, 1024, 0, stream>>>(
        (const f32x4*)x, cw, cb, sw, sb, (f32x4*)out, nX1);
}